// Round 1
// baseline (382.613 us; speedup 1.0000x reference)
//
#include <hip/hip_runtime.h>
#include <stdint.h>

#define NCLS 36
#define HDIM 256
#define BSZ  32
#define LLOC 196
#define DIN  1024
#define NCH  9216          // NCLS*HDIM
#define NCH4 2304          // NCH/4
#define XG_N 294912        // BSZ*NCH
#define SC_N 225792        // BSZ*NCLS*LLOC
#define V_N  1179648       // BSZ*NCLS*DIN

// ---------------------------------------------------------------------------
// kA: xg[b][n] = sum_{k=0..1023} gap[b][k]*Wg[k][n]   (bg added later in kC)
// grid 288 (n-tiles of 32), 512 thr, 1 block/CU. Full gap (128 KB) in LDS.
// thread = (n 0..31, bq 0..7 -> 4 b, kq 0..1 -> 512 k). Wg read ONCE, coalesced.
__global__ __launch_bounds__(512) void kA_xg(
    const float* __restrict__ Wg, const float* __restrict__ gap,
    float* __restrict__ XG) {
  __shared__ __align__(16) float4 gs[8192];      // [32 b][256 kg] = 128 KB
  const int tid = threadIdx.x;
  const int n0 = blockIdx.x * 32;
  const float4* gap4 = (const float4*)gap;
  for (int i = tid; i < 8192; i += 512) gs[i] = gap4[i];
  __syncthreads();
  const int n  = tid & 31;
  const int bq = (tid >> 5) & 7;
  const int kq = tid >> 8;
  float acc[4] = {0.f, 0.f, 0.f, 0.f};
  const float* wp = Wg + (size_t)(kq * 512) * NCH + n0 + n;
  const float4* gb = gs + kq * 128;
  #pragma unroll 4
  for (int k4 = 0; k4 < 128; ++k4) {
    float w0 = wp[(size_t)(k4 * 4 + 0) * NCH];
    float w1 = wp[(size_t)(k4 * 4 + 1) * NCH];
    float w2 = wp[(size_t)(k4 * 4 + 2) * NCH];
    float w3 = wp[(size_t)(k4 * 4 + 3) * NCH];
    #pragma unroll
    for (int bi = 0; bi < 4; ++bi) {
      float4 g = gb[(bq * 4 + bi) * 256 + k4];   // LDS broadcast (per b)
      acc[bi] += g.x * w0 + g.y * w1 + g.z * w2 + g.w * w3;
    }
  }
  __syncthreads();                                // all gs reads done
  float* red = (float*)gs;                        // alias: [2 kq][32 b][32 n]
  #pragma unroll
  for (int bi = 0; bi < 4; ++bi) red[kq * 1024 + (bq * 4 + bi) * 32 + n] = acc[bi];
  __syncthreads();
  for (int i = tid; i < 1024; i += 512)
    XG[(size_t)(i >> 5) * NCH + n0 + (i & 31)] = red[i] + red[1024 + i];
}

// ---------------------------------------------------------------------------
// kC: V[b][c][k] = sum_h (xg[b][c*256+h]+bg[c*256+h]) * Wl[k][c*256+h]
// grid (36 c, 16 kt64), 512 thr. Wl tile [64k][256h] staged coalesced (1 KB
// rows) + rotation swizzle for conflict-free per-lane-k ds_read_b128.
__global__ __launch_bounds__(512) void kC_V(
    const float* __restrict__ Wl, const float* __restrict__ XG,
    const float* __restrict__ bg, float* __restrict__ V) {
  __shared__ __align__(16) float4 wl_s[64 * 64];  // 64 KB, rotated rows
  __shared__ __align__(16) float4 xg_s[32 * 64];  // 32 KB
  const int tid = threadIdx.x;
  const int c = blockIdx.x, kt = blockIdx.y;
  const int k0 = kt * 64;
  const float4* wl4 = (const float4*)Wl;
  for (int i = tid; i < 4096; i += 512) {
    int r = i >> 6, g = i & 63;
    wl_s[r * 64 + ((g + r) & 63)] = wl4[(size_t)(k0 + r) * NCH4 + c * 64 + g];
  }
  const float4* xg4 = (const float4*)XG;
  const float4* bg4 = (const float4*)bg;
  for (int i = tid; i < 2048; i += 512) {
    int b = i >> 6, g = i & 63;
    float4 t = xg4[(size_t)b * NCH4 + c * 64 + g];
    float4 bv = bg4[c * 64 + g];
    t.x += bv.x; t.y += bv.y; t.z += bv.z; t.w += bv.w;
    xg_s[i] = t;
  }
  __syncthreads();
  const int k  = tid & 63;
  const int bq = tid >> 6;                        // 8 groups x 4 b
  float acc[4] = {0.f, 0.f, 0.f, 0.f};
  #pragma unroll 4
  for (int h4 = 0; h4 < 64; ++h4) {
    float4 w = wl_s[k * 64 + ((h4 + k) & 63)];    // conflict-free (rotation)
    #pragma unroll
    for (int bi = 0; bi < 4; ++bi) {
      float4 x = xg_s[(bq * 4 + bi) * 64 + h4];   // broadcast
      acc[bi] += w.x * x.x + w.y * x.y + w.z * x.z + w.w * x.w;
    }
  }
  #pragma unroll
  for (int bi = 0; bi < 4; ++bi)
    V[(size_t)((bq * 4 + bi) * NCLS + c) * DIN + k0 + k] = acc[bi];
}

// ---------------------------------------------------------------------------
// kD: scp[ks][b][c][l] = sum_{k chunk128} local[b][l][k]*V[b][c][k]
// grid (32 b, 8 ks) = 256 blocks = 1/CU, 512 thr. local slice (98 KB) staged
// ONCE, rotation-swizzled; all 36 c per block (no cg re-read).
__global__ __launch_bounds__(512) void kD_scores(
    const float* __restrict__ local_f, const float* __restrict__ V,
    float* __restrict__ SCP) {
  __shared__ __align__(16) float4 loc_s[196 * 32]; // 98 KB, rotated rows
  __shared__ __align__(16) float4 v_s[36 * 32];    // 18 KB
  const int tid = threadIdx.x;
  const int b = blockIdx.x, ks = blockIdx.y;
  const float4* lf4 = (const float4*)local_f;
  for (int i = tid; i < 6272; i += 512) {
    int r = i >> 5, g = i & 31;
    loc_s[r * 32 + ((g + r) & 31)] = lf4[(size_t)(b * LLOC + r) * 256 + ks * 32 + g];
  }
  const float4* v4 = (const float4*)V;
  for (int i = tid; i < 1152; i += 512) {
    int cc = i >> 5, g = i & 31;
    v_s[i] = v4[(size_t)(b * NCLS + cc) * 256 + ks * 32 + g];
  }
  __syncthreads();
  const int l  = tid & 255;
  const int ch = tid >> 8;                         // 0/1 -> 18 c each
  if (l >= LLOC) return;
  float acc[18] = {};
  #pragma unroll 4
  for (int k4 = 0; k4 < 32; ++k4) {
    float4 a = loc_s[l * 32 + ((k4 + l) & 31)];    // conflict-free (rotation)
    #pragma unroll
    for (int ci = 0; ci < 18; ++ci) {
      float4 v = v_s[(ch * 18 + ci) * 32 + k4];    // broadcast
      acc[ci] += a.x * v.x + a.y * v.y + a.z * v.z + a.w * v.w;
    }
  }
  #pragma unroll
  for (int ci = 0; ci < 18; ++ci)
    SCP[(size_t)ks * SC_N + (size_t)(b * NCLS + ch * 18 + ci) * LLOC + l] = acc[ci];
}

// ---------------------------------------------------------------------------
// kE: sum 8 partials + softmax over l; write attn2[b][c][l]. grid (32,36) x 64.
__global__ __launch_bounds__(64) void kE_softmax(
    const float* __restrict__ SCP, float* __restrict__ attn2) {
  const int b = blockIdx.x, c = blockIdx.y, t = threadIdx.x;
  const size_t base = (size_t)(b * NCLS + c) * LLOC;
  float sc[4];
  int nl = 0;
  float m = -1e30f;
  for (int l = t; l < LLOC; l += 64) {
    float s = 0.f;
    #pragma unroll
    for (int p = 0; p < 8; ++p) s += SCP[(size_t)p * SC_N + base + l];
    sc[nl++] = s; m = fmaxf(m, s);
  }
  #pragma unroll
  for (int off = 32; off >= 1; off >>= 1) m = fmaxf(m, __shfl_xor(m, off));
  float sum = 0.f;
  for (int i = 0; i < nl; ++i) { sc[i] = __expf(sc[i] - m); sum += sc[i]; }
  #pragma unroll
  for (int off = 32; off >= 1; off >>= 1) sum += __shfl_xor(sum, off);
  float inv = 1.0f / sum;
  nl = 0;
  for (int l = t; l < LLOC; l += 64) attn2[base + l] = sc[nl++] * inv;
}

// ---------------------------------------------------------------------------
// kF: U[b][c][k] = sum_l attn2[b][c][l]*local[b][l][k]
// grid (32 b, 8 ks) = 256 blocks = 1/CU, 512 thr. Same staged local slice;
// lanes read along rotated rows (contiguous floats -> conflict-free).
__global__ __launch_bounds__(512) void kF_U(
    const float* __restrict__ local_f, const float* __restrict__ attn,
    float* __restrict__ U) {
  __shared__ __align__(16) float4 loc_s[196 * 32]; // 98 KB, rotated rows
  __shared__ __align__(16) float4 at_s[36 * 49];   // 27.6 KB
  const int tid = threadIdx.x;
  const int b = blockIdx.x, ks = blockIdx.y;
  const float4* lf4 = (const float4*)local_f;
  for (int i = tid; i < 6272; i += 512) {
    int r = i >> 5, g = i & 31;
    loc_s[r * 32 + ((g + r) & 31)] = lf4[(size_t)(b * LLOC + r) * 256 + ks * 32 + g];
  }
  const float4* at4 = (const float4*)attn;
  for (int i = tid; i < 1764; i += 512) {
    int cc = i / 49, g = i - cc * 49;
    at_s[i] = at4[(size_t)(b * NCLS + cc) * 49 + g];
  }
  __syncthreads();
  const int kk = tid & 127;
  const int cq = tid >> 7;                         // 4 groups x 9 c
  const int g0 = kk >> 2, ksub = kk & 3;
  const float* ls = (const float*)loc_s;
  float acc[9] = {};
  for (int l4 = 0; l4 < 49; ++l4) {
    const int l = l4 * 4;
    float a0 = ls[((l + 0) * 32 + ((g0 + l + 0) & 31)) * 4 + ksub];
    float a1 = ls[((l + 1) * 32 + ((g0 + l + 1) & 31)) * 4 + ksub];
    float a2 = ls[((l + 2) * 32 + ((g0 + l + 2) & 31)) * 4 + ksub];
    float a3 = ls[((l + 3) * 32 + ((g0 + l + 3) & 31)) * 4 + ksub];
    #pragma unroll
    for (int ci = 0; ci < 9; ++ci) {
      float4 w = at_s[(cq * 9 + ci) * 49 + l4];    // broadcast
      acc[ci] += a0 * w.x + a1 * w.y + a2 * w.z + a3 * w.w;
    }
  }
  #pragma unroll
  for (int ci = 0; ci < 9; ++ci)
    U[(size_t)(b * NCLS + cq * 9 + ci) * DIN + ks * 128 + kk] = acc[ci];
}

// ---------------------------------------------------------------------------
// kG: ws[b][c*256+h] = sum_{k=0..1023} U[b][c][k]*Wl[k][c*256+h] + bl[...]
// grid 288 (n-tiles of 32: c = nt>>3), 512 thr, full-k per block.
// Wl read ONCE, coalesced. U rows (128 KB) staged in LDS.
__global__ __launch_bounds__(512) void kG_ws(
    const float* __restrict__ Wl, const float* __restrict__ U,
    const float* __restrict__ bl, float* __restrict__ WS) {
  __shared__ __align__(16) float4 us[8192];        // [32 b][256 kg] = 128 KB
  const int tid = threadIdx.x;
  const int nt = blockIdx.x;
  const int c = nt >> 3, h0 = (nt & 7) * 32;
  const float4* u4 = (const float4*)U;
  for (int i = tid; i < 8192; i += 512) {
    int b = i >> 8, g = i & 255;
    us[i] = u4[(size_t)(b * NCLS + c) * 256 + g];
  }
  __syncthreads();
  const int n  = tid & 31;
  const int bq = (tid >> 5) & 7;
  const int kq = tid >> 8;
  float acc[4] = {0.f, 0.f, 0.f, 0.f};
  const float* wp = Wl + (size_t)(kq * 512) * NCH + c * 256 + h0 + n;
  const float4* ub = us + kq * 128;
  #pragma unroll 4
  for (int k4 = 0; k4 < 128; ++k4) {
    float w0 = wp[(size_t)(k4 * 4 + 0) * NCH];
    float w1 = wp[(size_t)(k4 * 4 + 1) * NCH];
    float w2 = wp[(size_t)(k4 * 4 + 2) * NCH];
    float w3 = wp[(size_t)(k4 * 4 + 3) * NCH];
    #pragma unroll
    for (int bi = 0; bi < 4; ++bi) {
      float4 g = ub[(bq * 4 + bi) * 256 + k4];     // LDS broadcast (per b)
      acc[bi] += g.x * w0 + g.y * w1 + g.z * w2 + g.w * w3;
    }
  }
  __syncthreads();
  float* red = (float*)us;                          // alias: [2][32 b][32 n]
  #pragma unroll
  for (int bi = 0; bi < 4; ++bi) red[kq * 1024 + (bq * 4 + bi) * 32 + n] = acc[bi];
  __syncthreads();
  for (int i = tid; i < 1024; i += 512) {
    int bb = i >> 5, nn = i & 31;
    WS[(size_t)bb * NCH + c * 256 + h0 + nn] =
        red[i] + red[1024 + i] + bl[c * 256 + h0 + nn];
  }
}

// ---------------------------------------------------------------------------
// kH: hid = relu(ws@Wh+bh); heads. grid (32,12) x 256. (bl already in ws.)
__global__ __launch_bounds__(256) void kH_heads(
    const float* __restrict__ Wh, const float* __restrict__ bh,
    const float* __restrict__ Wr, const float* __restrict__ br,
    const float* __restrict__ Wc, const float* __restrict__ bc,
    const float* __restrict__ WS, float* __restrict__ out) {
  __shared__ float ws_s[3][HDIM];
  __shared__ float hid_s[3][HDIM];
  const int b = blockIdx.x, c0 = blockIdx.y * 3;
  const int j = threadIdx.x;
  #pragma unroll
  for (int ci = 0; ci < 3; ++ci)
    ws_s[ci][j] = WS[(size_t)b * NCH + (c0 + ci) * HDIM + j];
  __syncthreads();
  float acc[3] = {0, 0, 0};
  for (int h = 0; h < HDIM; ++h) {
    float whj = Wh[(size_t)h * HDIM + j];
    acc[0] += ws_s[0][h] * whj;
    acc[1] += ws_s[1][h] * whj;
    acc[2] += ws_s[2][h] * whj;
  }
  float bj = bh[j];
  #pragma unroll
  for (int ci = 0; ci < 3; ++ci) hid_s[ci][j] = fmaxf(acc[ci] + bj, 0.0f);
  __syncthreads();
  const int r = j >> 6, j0 = j & 63;
  for (int ci = 0; ci < 3; ++ci) {
    const int c = c0 + ci;
    float s = 0.f;
    #pragma unroll
    for (int m = 0; m < 4; ++m)
      s += hid_s[ci][j0 + 64 * m] * Wr[(j0 + 64 * m) * 4 + r];
    #pragma unroll
    for (int off = 32; off >= 1; off >>= 1) s += __shfl_xor(s, off);
    if (j0 == 0) out[(size_t)b * (NCLS * 4) + c * 4 + r] = s + br[r];
    if (r == 0) {
      float p = 0.f;
      #pragma unroll
      for (int m = 0; m < 4; ++m)
        p += hid_s[ci][j0 + 64 * m] * Wc[j0 + 64 * m];
      #pragma unroll
      for (int off = 32; off >= 1; off >>= 1) p += __shfl_xor(p, off);
      if (j0 == 0) out[BSZ * NCLS * 4 + b * NCLS + c] = p + bc[0];
    }
  }
}

// ---------------------------------------------------------------------------
extern "C" void kernel_launch(void* const* d_in, const int* in_sizes, int n_in,
                              void* d_out, int out_size, void* d_ws, size_t ws_size,
                              hipStream_t stream) {
  const float* local = (const float*)d_in[0];
  const float* gap   = (const float*)d_in[1];
  const float* Wl    = (const float*)d_in[2];
  const float* bl    = (const float*)d_in[3];
  const float* Wg    = (const float*)d_in[4];
  const float* bg    = (const float*)d_in[5];
  const float* Wh    = (const float*)d_in[6];
  const float* bh    = (const float*)d_in[7];
  const float* Wr    = (const float*)d_in[8];
  const float* br    = (const float*)d_in[9];
  const float* Wc    = (const float*)d_in[10];
  const float* bc    = (const float*)d_in[11];
  float* out         = (float*)d_out;

  // workspace: xg 1.2MB | V 4.7MB | scp 7.2MB | attn 0.9MB | U 4.7MB | ws 1.2MB
  float* XG   = (float*)d_ws;
  float* V    = XG + XG_N;
  float* SCP  = V + V_N;
  float* ATT  = SCP + (size_t)8 * SC_N;
  float* U    = ATT + SC_N;
  float* WS   = U + V_N;

  kA_xg     <<<dim3(288),    dim3(512), 0, stream>>>(Wg, gap, XG);
  kC_V      <<<dim3(36, 16), dim3(512), 0, stream>>>(Wl, XG, bg, V);
  kD_scores <<<dim3(32, 8),  dim3(512), 0, stream>>>(local, V, SCP);
  kE_softmax<<<dim3(32, 36), dim3(64),  0, stream>>>(SCP, ATT);
  kF_U      <<<dim3(32, 8),  dim3(512), 0, stream>>>(local, ATT, U);
  kG_ws     <<<dim3(288),    dim3(512), 0, stream>>>(Wl, U, bl, WS);
  kH_heads  <<<dim3(32, 12), dim3(256), 0, stream>>>(Wh, bh, Wr, br, Wc, bc, WS, out);
}

// Round 2
// 271.243 us; speedup vs baseline: 1.4106x; 1.4106x over previous
//
#include <hip/hip_runtime.h>
#include <stdint.h>

#define NCLS 36
#define HDIM 256
#define BSZ  32
#define LLOC 196
#define DIN  1024
#define NCH  9216          // NCLS*HDIM
#define NCH4 2304          // NCH/4
#define XG_N 294912        // BSZ*NCH
#define SC_N 225792        // BSZ*NCLS*LLOC
#define V_N  1179648       // BSZ*NCLS*DIN

__device__ __forceinline__ void fma4(float4& a, float s, const float4& b) {
  a.x += s * b.x; a.y += s * b.y; a.z += s * b.z; a.w += s * b.w;
}
__device__ __forceinline__ float dot4(const float4& a, const float4& b) {
  return a.x * b.x + a.y * b.y + a.z * b.z + a.w * b.w;
}

// ---------------------------------------------------------------------------
// kA: XGP[ks][b][n] = sum_{k in ks*64..+64} gap[b][k]*Wg[k][n]
// grid (36 nt256, 16 ks64), 256 thr, 8 KB LDS (2+ blocks/CU).
// thread: ng=tid&31 -> n = n0+ng*4 (+128), bq=tid>>5 -> 4 b.
// Per k4: 8 float4 Wg loads + 4 LDS b128 (broadcast) -> 128 FMA. VALU-bound.
__global__ __launch_bounds__(256) void kA_xg(
    const float* __restrict__ Wg, const float* __restrict__ gap,
    float* __restrict__ XGP) {
  __shared__ __align__(16) float4 gs[512];          // [32 b][16 k4] = 8 KB
  const int tid = threadIdx.x;
  const int nt = blockIdx.x, ks = blockIdx.y;
  const int n0 = nt * 256, k0 = ks * 64;
  const float4* gap4 = (const float4*)gap;
  for (int i = tid; i < 512; i += 256)
    gs[i] = gap4[(size_t)(i >> 4) * 256 + ks * 16 + (i & 15)];
  __syncthreads();
  const int ng = tid & 31, bq = tid >> 5;
  const int b0 = bq * 4;
  float4 acc0[4] = {}; float4 acc1[4] = {};
  const float* wp = Wg + (size_t)k0 * NCH + n0 + ng * 4;
  for (int k4 = 0; k4 < 16; ++k4) {
    float4 w0[4], w1[4];
    #pragma unroll
    for (int kk = 0; kk < 4; ++kk) {
      const float* p = wp + (size_t)(k4 * 4 + kk) * NCH;
      w0[kk] = *(const float4*)p;
      w1[kk] = *(const float4*)(p + 128);
    }
    #pragma unroll
    for (int bb = 0; bb < 4; ++bb) {
      float4 g = gs[(b0 + bb) * 16 + k4];
      fma4(acc0[bb], g.x, w0[0]); fma4(acc0[bb], g.y, w0[1]);
      fma4(acc0[bb], g.z, w0[2]); fma4(acc0[bb], g.w, w0[3]);
      fma4(acc1[bb], g.x, w1[0]); fma4(acc1[bb], g.y, w1[1]);
      fma4(acc1[bb], g.z, w1[2]); fma4(acc1[bb], g.w, w1[3]);
    }
  }
  #pragma unroll
  for (int bb = 0; bb < 4; ++bb) {
    size_t o = (size_t)ks * XG_N + (size_t)(b0 + bb) * NCH + n0 + ng * 4;
    *(float4*)&XGP[o]       = acc0[bb];
    *(float4*)&XGP[o + 128] = acc1[bb];
  }
}

// ---------------------------------------------------------------------------
// kB: XG[i] = sum_{p<16} XGP[p][i].  73728 f4 -> 288 blocks x 256.
__global__ __launch_bounds__(256) void kB_red(
    const float* __restrict__ XGP, float* __restrict__ XG) {
  const int i = blockIdx.x * 256 + threadIdx.x;
  const float4* p4 = (const float4*)XGP;
  float4 s = p4[i];
  #pragma unroll
  for (int p = 1; p < 16; ++p) {
    float4 t = p4[(size_t)p * (XG_N / 4) + i];
    s.x += t.x; s.y += t.y; s.z += t.z; s.w += t.w;
  }
  ((float4*)XG)[i] = s;
}

// ---------------------------------------------------------------------------
// kC: V[b][c][k] = sum_h (XG[b][c,h]+bg[c,h]) * Wl[k][c*256+h]
// grid (36 c, 8 kt128), 512 thr, 32 KB LDS. lane: q=lane&3 (h-offset),
// r=lane>>2 (16 row-groups); wave w -> 4 b. thread tile: 8 k x 4 b.
// Per it: 8 float4 Wl loads + 4 LDS b128 -> 128 FMA. q-partials via shfl.
__global__ __launch_bounds__(512) void kC_V(
    const float* __restrict__ Wl, const float* __restrict__ XG,
    const float* __restrict__ bg, float* __restrict__ V) {
  __shared__ __align__(16) float4 xs[2048];         // [32 b][64 h4] = 32 KB
  const int tid = threadIdx.x;
  const int c = blockIdx.x, kt = blockIdx.y;
  const float4* xg4 = (const float4*)XG;
  const float4* bg4 = (const float4*)bg;
  for (int i = tid; i < 2048; i += 512) {
    int b = i >> 6, h4 = i & 63;
    float4 t = xg4[(size_t)b * NCH4 + c * 64 + h4];
    float4 bv = bg4[c * 64 + h4];
    t.x += bv.x; t.y += bv.y; t.z += bv.z; t.w += bv.w;
    xs[i] = t;
  }
  __syncthreads();
  const int lane = tid & 63, w = tid >> 6;
  const int q = lane & 3, r = lane >> 2;
  const int b0 = w * 4;
  const int krow = kt * 128 + r * 8;
  float acc[4][8] = {};
  const float* wl = Wl + (size_t)krow * NCH + c * 256 + q * 4;
  for (int it = 0; it < 16; ++it) {
    float4 wv[8];
    #pragma unroll
    for (int kk = 0; kk < 8; ++kk)
      wv[kk] = *(const float4*)(wl + (size_t)kk * NCH + it * 16);
    #pragma unroll
    for (int bb = 0; bb < 4; ++bb) {
      float4 x = xs[(b0 + bb) * 64 + it * 4 + q];
      #pragma unroll
      for (int kk = 0; kk < 8; ++kk)
        acc[bb][kk] += dot4(wv[kk], x);
    }
  }
  #pragma unroll
  for (int bb = 0; bb < 4; ++bb) {
    #pragma unroll
    for (int kk = 0; kk < 8; ++kk) {
      float s = acc[bb][kk];
      s += __shfl_xor(s, 1); s += __shfl_xor(s, 2);
      acc[bb][kk] = s;
    }
  }
  if (q == 0) {
    #pragma unroll
    for (int bb = 0; bb < 4; ++bb)
      #pragma unroll
      for (int kk = 0; kk < 8; ++kk)
        V[(size_t)((b0 + bb) * NCLS + c) * DIN + krow + kk] = acc[bb][kk];
  }
}

// ---------------------------------------------------------------------------
// kD: SCP[ks][b][c][l] = sum_{k in ks*64..+64} loc[b][l][k]*V[b][c][k]
// grid (32 b, 16 ks64) = 512 (2 blocks/CU at 58 KB), 256 thr.
// loc rows rotation-swizzled (lanes read consecutive rows -> conflict-free).
// thread tile: 4 l (lg+64i) x 9 c.  Per k4: ~13 LDS b128 -> 144 FMA.
__global__ __launch_bounds__(256) void kD_scores(
    const float* __restrict__ local_f, const float* __restrict__ V,
    float* __restrict__ SCP) {
  __shared__ __align__(16) float4 loc_s[3136];      // [196][16] rot = 49 KB
  __shared__ __align__(16) float4 v_s[576];         // [36][16] = 9 KB
  const int tid = threadIdx.x;
  const int b = blockIdx.x, ks = blockIdx.y;
  const float4* lf4 = (const float4*)local_f;
  for (int i = tid; i < 3136; i += 256) {
    int r = i >> 4, g = i & 15;
    loc_s[r * 16 + ((g + r) & 15)] = lf4[(size_t)(b * LLOC + r) * 256 + ks * 16 + g];
  }
  const float4* v4 = (const float4*)V;
  for (int i = tid; i < 576; i += 256) {
    int cc = i >> 4, g = i & 15;
    v_s[i] = v4[(size_t)(b * NCLS + cc) * 256 + ks * 16 + g];
  }
  __syncthreads();
  const int lg = tid & 63, cg = tid >> 6;
  float acc[4][9] = {};
  for (int k4 = 0; k4 < 16; ++k4) {
    float4 vv[9];
    #pragma unroll
    for (int ci = 0; ci < 9; ++ci) vv[ci] = v_s[(cg * 9 + ci) * 16 + k4];
    #pragma unroll
    for (int i = 0; i < 4; ++i) {
      int l = lg + 64 * i;
      if (l < LLOC) {
        float4 a = loc_s[l * 16 + ((k4 + l) & 15)];
        #pragma unroll
        for (int ci = 0; ci < 9; ++ci) acc[i][ci] += dot4(a, vv[ci]);
      }
    }
  }
  #pragma unroll
  for (int i = 0; i < 4; ++i) {
    int l = lg + 64 * i;
    if (l < LLOC) {
      #pragma unroll
      for (int ci = 0; ci < 9; ++ci)
        SCP[(size_t)ks * SC_N + (size_t)(b * NCLS + cg * 9 + ci) * LLOC + l] = acc[i][ci];
    }
  }
}

// ---------------------------------------------------------------------------
// kE: sum 16 partials + softmax over l. grid (32,36) x 64.
__global__ __launch_bounds__(64) void kE_softmax(
    const float* __restrict__ SCP, float* __restrict__ attn2) {
  const int b = blockIdx.x, c = blockIdx.y, t = threadIdx.x;
  const size_t base = (size_t)(b * NCLS + c) * LLOC;
  float sc[4];
  int nl = 0;
  float m = -1e30f;
  for (int l = t; l < LLOC; l += 64) {
    float s = 0.f;
    #pragma unroll
    for (int p = 0; p < 16; ++p) s += SCP[(size_t)p * SC_N + base + l];
    sc[nl++] = s; m = fmaxf(m, s);
  }
  #pragma unroll
  for (int off = 32; off >= 1; off >>= 1) m = fmaxf(m, __shfl_xor(m, off));
  float sum = 0.f;
  for (int i = 0; i < nl; ++i) { sc[i] = __expf(sc[i] - m); sum += sc[i]; }
  #pragma unroll
  for (int off = 32; off >= 1; off >>= 1) sum += __shfl_xor(sum, off);
  float inv = 1.0f / sum;
  nl = 0;
  for (int l = t; l < LLOC; l += 64) attn2[base + l] = sc[nl++] * inv;
}

// ---------------------------------------------------------------------------
// kF: U[b][c][k] = sum_l att[b][c][l]*loc[b][l][k]
// grid (32 b, 8 ks128) = 256 = 1/CU, 256 thr. loc streamed from GLOBAL
// (coalesced, L2-resident); att (27.6 KB) + lh-reduce (72 KB) in LDS.
// thread: kg=tid&15 (8 k), cg=(tid>>4)&3 (9 c), lh=tid>>6 (l4 = lh,lh+4,..).
__global__ __launch_bounds__(256) void kF_U(
    const float* __restrict__ local_f, const float* __restrict__ ATT,
    float* __restrict__ U) {
  __shared__ __align__(16) float4 att_s[1764];      // [36][49] = 27.6 KB
  __shared__ __align__(16) float4 red[4608];        // [4][36][32] = 72 KB
  const int tid = threadIdx.x;
  const int b = blockIdx.x, ks = blockIdx.y;
  const int k0 = ks * 128;
  const float4* at4 = (const float4*)ATT;
  for (int i = tid; i < 1764; i += 256) {
    int cc = i / 49, l4 = i - cc * 49;
    att_s[i] = at4[(size_t)(b * NCLS + cc) * 49 + l4];
  }
  __syncthreads();
  const int kg = tid & 15, cg = (tid >> 4) & 3, lh = tid >> 6;
  float4 acc[9][2] = {};
  const float* lbase = local_f + (size_t)b * LLOC * DIN + k0 + kg * 8;
  for (int l4 = lh; l4 < 49; l4 += 4) {
    float4 lv[4][2];
    #pragma unroll
    for (int ll = 0; ll < 4; ++ll) {
      const float* p = lbase + (size_t)(l4 * 4 + ll) * DIN;
      lv[ll][0] = *(const float4*)p;
      lv[ll][1] = *(const float4*)(p + 4);
    }
    #pragma unroll
    for (int ci = 0; ci < 9; ++ci) {
      float4 av = att_s[(cg * 9 + ci) * 49 + l4];
      fma4(acc[ci][0], av.x, lv[0][0]); fma4(acc[ci][1], av.x, lv[0][1]);
      fma4(acc[ci][0], av.y, lv[1][0]); fma4(acc[ci][1], av.y, lv[1][1]);
      fma4(acc[ci][0], av.z, lv[2][0]); fma4(acc[ci][1], av.z, lv[2][1]);
      fma4(acc[ci][0], av.w, lv[3][0]); fma4(acc[ci][1], av.w, lv[3][1]);
    }
  }
  #pragma unroll
  for (int ci = 0; ci < 9; ++ci) {
    int c = cg * 9 + ci;
    red[lh * 1152 + c * 32 + kg * 2 + 0] = acc[ci][0];
    red[lh * 1152 + c * 32 + kg * 2 + 1] = acc[ci][1];
  }
  __syncthreads();
  float4* u4 = (float4*)U;
  for (int i = tid; i < 1152; i += 256) {
    float4 s = red[i];
    #pragma unroll
    for (int p = 1; p < 4; ++p) {
      float4 t = red[p * 1152 + i];
      s.x += t.x; s.y += t.y; s.z += t.z; s.w += t.w;
    }
    u4[(size_t)(b * NCLS + (i >> 5)) * 256 + ks * 32 + (i & 31)] = s;
  }
}

// ---------------------------------------------------------------------------
// kG: WSP[ks][b][c*256+h] = sum_{k in ks*64..+64} U[b][c][k]*Wl[k][c*256+h]
// Same structure as kA. grid (36 c, 16 ks64), 256 thr, 8 KB LDS.
__global__ __launch_bounds__(256) void kG_ws(
    const float* __restrict__ Wl, const float* __restrict__ U,
    float* __restrict__ WSP) {
  __shared__ __align__(16) float4 us[512];          // [32 b][16 k4] = 8 KB
  const int tid = threadIdx.x;
  const int c = blockIdx.x, ks = blockIdx.y;
  const int k0 = ks * 64;
  const float4* u4 = (const float4*)U;
  for (int i = tid; i < 512; i += 256)
    us[i] = u4[(size_t)((i >> 4) * NCLS + c) * 256 + ks * 16 + (i & 15)];
  __syncthreads();
  const int ng = tid & 31, bq = tid >> 5;
  const int b0 = bq * 4;
  float4 acc0[4] = {}; float4 acc1[4] = {};
  const float* wp = Wl + (size_t)k0 * NCH + c * 256 + ng * 4;
  for (int k4 = 0; k4 < 16; ++k4) {
    float4 w0[4], w1[4];
    #pragma unroll
    for (int kk = 0; kk < 4; ++kk) {
      const float* p = wp + (size_t)(k4 * 4 + kk) * NCH;
      w0[kk] = *(const float4*)p;
      w1[kk] = *(const float4*)(p + 128);
    }
    #pragma unroll
    for (int bb = 0; bb < 4; ++bb) {
      float4 g = us[(b0 + bb) * 16 + k4];
      fma4(acc0[bb], g.x, w0[0]); fma4(acc0[bb], g.y, w0[1]);
      fma4(acc0[bb], g.z, w0[2]); fma4(acc0[bb], g.w, w0[3]);
      fma4(acc1[bb], g.x, w1[0]); fma4(acc1[bb], g.y, w1[1]);
      fma4(acc1[bb], g.z, w1[2]); fma4(acc1[bb], g.w, w1[3]);
    }
  }
  #pragma unroll
  for (int bb = 0; bb < 4; ++bb) {
    size_t o = (size_t)ks * XG_N + (size_t)(b0 + bb) * NCH + c * 256 + ng * 4;
    *(float4*)&WSP[o]       = acc0[bb];
    *(float4*)&WSP[o + 128] = acc1[bb];
  }
}

// ---------------------------------------------------------------------------
// kH: ws = bl + sum16 WSP; hid = relu(ws@Wh+bh); heads. grid (32,12) x 256.
__global__ __launch_bounds__(256) void kH_heads(
    const float* __restrict__ Wh, const float* __restrict__ bh,
    const float* __restrict__ Wr, const float* __restrict__ br,
    const float* __restrict__ Wc, const float* __restrict__ bc,
    const float* __restrict__ bl,
    const float* __restrict__ WSP, float* __restrict__ out) {
  __shared__ float ws_s[3][HDIM];
  __shared__ float hid_s[3][HDIM];
  const int b = blockIdx.x, c0 = blockIdx.y * 3;
  const int j = threadIdx.x;
  #pragma unroll
  for (int ci = 0; ci < 3; ++ci) {
    size_t base = (size_t)b * NCH + (c0 + ci) * HDIM + j;
    float s = bl[(c0 + ci) * HDIM + j];
    #pragma unroll
    for (int p = 0; p < 16; ++p) s += WSP[(size_t)p * XG_N + base];
    ws_s[ci][j] = s;
  }
  __syncthreads();
  float acc[3] = {0, 0, 0};
  for (int h = 0; h < HDIM; ++h) {
    float whj = Wh[(size_t)h * HDIM + j];
    acc[0] += ws_s[0][h] * whj;
    acc[1] += ws_s[1][h] * whj;
    acc[2] += ws_s[2][h] * whj;
  }
  float bj = bh[j];
  #pragma unroll
  for (int ci = 0; ci < 3; ++ci) hid_s[ci][j] = fmaxf(acc[ci] + bj, 0.0f);
  __syncthreads();
  const int r = j >> 6, j0 = j & 63;
  for (int ci = 0; ci < 3; ++ci) {
    const int c = c0 + ci;
    float s = 0.f;
    #pragma unroll
    for (int m = 0; m < 4; ++m)
      s += hid_s[ci][j0 + 64 * m] * Wr[(j0 + 64 * m) * 4 + r];
    #pragma unroll
    for (int off = 32; off >= 1; off >>= 1) s += __shfl_xor(s, off);
    if (j0 == 0) out[(size_t)b * (NCLS * 4) + c * 4 + r] = s + br[r];
    if (r == 0) {
      float p = 0.f;
      #pragma unroll
      for (int m = 0; m < 4; ++m)
        p += hid_s[ci][j0 + 64 * m] * Wc[j0 + 64 * m];
      #pragma unroll
      for (int off = 32; off >= 1; off >>= 1) p += __shfl_xor(p, off);
      if (j0 == 0) out[BSZ * NCLS * 4 + b * NCLS + c] = p + bc[0];
    }
  }
}

// ---------------------------------------------------------------------------
extern "C" void kernel_launch(void* const* d_in, const int* in_sizes, int n_in,
                              void* d_out, int out_size, void* d_ws, size_t ws_size,
                              hipStream_t stream) {
  const float* local = (const float*)d_in[0];
  const float* gap   = (const float*)d_in[1];
  const float* Wl    = (const float*)d_in[2];
  const float* bl    = (const float*)d_in[3];
  const float* Wg    = (const float*)d_in[4];
  const float* bg    = (const float*)d_in[5];
  const float* Wh    = (const float*)d_in[6];
  const float* bh    = (const float*)d_in[7];
  const float* Wr    = (const float*)d_in[8];
  const float* br    = (const float*)d_in[9];
  const float* Wc    = (const float*)d_in[10];
  const float* bc    = (const float*)d_in[11];
  float* out         = (float*)d_out;

  // ws: XGP 16x1.2MB | XG 1.2 | V 4.7 | SCP 16x0.9 | ATT 0.9 | U 4.7 | WSP 16x1.2
  float* XGP = (float*)d_ws;
  float* XG  = XGP + (size_t)16 * XG_N;
  float* V   = XG + XG_N;
  float* SCP = V + V_N;
  float* ATT = SCP + (size_t)16 * SC_N;
  float* U   = ATT + SC_N;
  float* WSP = U + V_N;

  kA_xg     <<<dim3(36, 16), dim3(256), 0, stream>>>(Wg, gap, XGP);
  kB_red    <<<dim3(288),    dim3(256), 0, stream>>>(XGP, XG);
  kC_V      <<<dim3(36, 8),  dim3(512), 0, stream>>>(Wl, XG, bg, V);
  kD_scores <<<dim3(32, 16), dim3(256), 0, stream>>>(local, V, SCP);
  kE_softmax<<<dim3(32, 36), dim3(64),  0, stream>>>(SCP, ATT);
  kF_U      <<<dim3(32, 8),  dim3(256), 0, stream>>>(local, ATT, U);
  kG_ws     <<<dim3(36, 16), dim3(256), 0, stream>>>(Wl, U, WSP);
  kH_heads  <<<dim3(32, 12), dim3(256), 0, stream>>>(Wh, bh, Wr, br, Wc, bc, bl, WSP, out);
}